// Round 1
// baseline (88.275 us; speedup 1.0000x reference)
//
#include <hip/hip_runtime.h>
#include <math.h>

#define D_IN 768
#define NQ 12
#define NST 4096      // 2^12 states
#define NPAIR 2048
#define NT 256
#define NLAB 28

__global__ __launch_bounds__(NT) void hybrid_fused(
    const float* __restrict__ x,       // (B,768)
    const float* __restrict__ proj_w,  // (12,768)
    const float* __restrict__ proj_b,  // (12)
    const float* __restrict__ ln_w,    // (12)
    const float* __restrict__ ln_b,    // (12)
    const float* __restrict__ q_w,     // (3,12,3)
    const float* __restrict__ h1_w,    // (256,12)
    const float* __restrict__ h1_b,    // (256)
    const float* __restrict__ h2_w,    // (28,256)
    const float* __restrict__ h2_b,    // (28)
    float* __restrict__ out)           // (B,28)
{
    __shared__ float2 st[NST];          // 32 KB state vector
    __shared__ float rotU[3][NQ][8];    // Rot gate matrices (complex 2x2 each)
    __shared__ float hbuf[NQ];
    __shared__ float cy[NQ], sy[NQ];    // RY cos/sin of theta/2
    __shared__ float red[4 * NQ];
    __shared__ float z1[256];
    __shared__ float qz[NQ];

    const int b = blockIdx.x;
    const int tid = threadIdx.x;
    const int lane = tid & 63;
    const int wid = tid >> 6;

    // ---- 1. projection h[j] = tanh(x[b] . proj_w[j] + proj_b[j]) ----
    // wave wid handles outputs j = wid*3 .. wid*3+2
    {
        const float* xr = x + (size_t)b * D_IN;
        #pragma unroll
        for (int jj = 0; jj < 3; ++jj) {
            const int j = wid * 3 + jj;
            const float* wr = proj_w + j * D_IN;
            float s = 0.f;
            #pragma unroll
            for (int k = 0; k < D_IN / 64; ++k)
                s += xr[lane + k * 64] * wr[lane + k * 64];
            #pragma unroll
            for (int m = 32; m; m >>= 1) s += __shfl_xor(s, m, 64);
            if (lane == 0) hbuf[j] = tanhf(s + proj_b[j]);
        }
    }
    __syncthreads();

    // ---- 2. LayerNorm -> angles -> RY coeffs (threads 0..11), Rot mats (0..35) ----
    if (tid < NQ) {
        float mu = 0.f;
        #pragma unroll
        for (int k = 0; k < NQ; ++k) mu += hbuf[k];
        mu *= (1.f / NQ);
        float var = 0.f;
        #pragma unroll
        for (int k = 0; k < NQ; ++k) { float d = hbuf[k] - mu; var += d * d; }
        var *= (1.f / NQ);
        float inv = 1.0f / sqrtf(var + 1e-5f);
        float ang = (hbuf[tid] - mu) * inv * ln_w[tid] + ln_b[tid];
        cy[tid] = cosf(0.5f * ang);
        sy[tid] = sinf(0.5f * ang);
    }
    if (tid < 3 * NQ) {
        const int l = tid / NQ, w = tid % NQ;
        const float phi = q_w[(l * NQ + w) * 3 + 0];
        const float th  = q_w[(l * NQ + w) * 3 + 1];
        const float om  = q_w[(l * NQ + w) * 3 + 2];
        const float c = cosf(0.5f * th), s = sinf(0.5f * th);
        const float a  = 0.5f * (phi + om);
        const float bb = 0.5f * (phi - om);
        const float ca = cosf(a), sa = sinf(a);
        const float cb = cosf(bb), sb = sinf(bb);
        float* U = rotU[l][w];
        U[0] =  c * ca;  U[1] = -c * sa;   // U00 = ep*c
        U[2] = -s * cb;  U[3] = -s * sb;   // U01 = -conj(em)*s
        U[4] =  s * cb;  U[5] = -s * sb;   // U10 = em*s
        U[6] =  c * ca;  U[7] =  c * sa;   // U11 = conj(ep)*c
    }

    // ---- 3. init |0..0> ----
    #pragma unroll
    for (int k = 0; k < NST / NT; ++k) {
        const int i = tid + k * NT;
        st[i] = make_float2(i == 0 ? 1.f : 0.f, 0.f);
    }
    __syncthreads();

    // generic 1-qubit complex gate on bit position `bit`
    auto apply1q = [&](float u00r, float u00i, float u01r, float u01i,
                       float u10r, float u10i, float u11r, float u11i, int bit) {
        const int lowmask = (1 << bit) - 1;
        #pragma unroll
        for (int pp = 0; pp < NPAIR / NT; ++pp) {
            const int p = tid + pp * NT;
            const int i0 = ((p & ~lowmask) << 1) | (p & lowmask);
            const int i1 = i0 | (1 << bit);
            const float2 a0 = st[i0], a1 = st[i1];
            float2 n0, n1;
            n0.x = u00r * a0.x - u00i * a0.y + u01r * a1.x - u01i * a1.y;
            n0.y = u00r * a0.y + u00i * a0.x + u01r * a1.y + u01i * a1.x;
            n1.x = u10r * a0.x - u10i * a0.y + u11r * a1.x - u11i * a1.y;
            n1.y = u10r * a0.y + u10i * a0.x + u11r * a1.y + u11i * a1.x;
            st[i0] = n0; st[i1] = n1;
        }
        __syncthreads();
    };

    // CNOT: swap amplitudes where ctrl-bit=1 between tgt=0/1
    auto applyCnot = [&](int bc, int bt) {
        const int lo = bc < bt ? bc : bt;
        const int hi = bc < bt ? bt : bc;
        const int mlo = (1 << lo) - 1;
        const int mhi = (1 << hi) - 1;
        #pragma unroll
        for (int pp = 0; pp < (NST / 4) / NT; ++pp) {
            const int p = tid + pp * NT;
            int i = ((p & ~mlo) << 1) | (p & mlo);   // insert 0 at lo
            i = ((i & ~mhi) << 1) | (i & mhi);       // insert 0 at hi
            const int i0 = i | (1 << bc);            // ctrl=1, tgt=0
            const int i1 = i0 | (1 << bt);
            const float2 t0 = st[i0], t1 = st[i1];
            st[i0] = t1; st[i1] = t0;
        }
        __syncthreads();
    };

    // ---- 4. AngleEmbedding: RY(ang[w]) on wire w (bit 11-w) ----
    for (int w = 0; w < NQ; ++w) {
        const float c = cy[w], s = sy[w];
        apply1q(c, 0.f, -s, 0.f, s, 0.f, c, 0.f, 11 - w);
    }

    // ---- 5. StronglyEntanglingLayers ----
    for (int l = 0; l < 3; ++l) {
        for (int w = 0; w < NQ; ++w) {
            const float* U = rotU[l][w];
            apply1q(U[0], U[1], U[2], U[3], U[4], U[5], U[6], U[7], 11 - w);
        }
        const int r = l + 1;  // (l % 11) + 1 for l=0,1,2
        for (int w = 0; w < NQ; ++w) {
            const int tw = (w + r) % NQ;
            applyCnot(11 - w, 11 - tw);
        }
    }

    // ---- 6. PauliZ expectations ----
    float zl[NQ];
    #pragma unroll
    for (int w = 0; w < NQ; ++w) zl[w] = 0.f;
    #pragma unroll
    for (int k = 0; k < NST / NT; ++k) {
        const int i = tid + k * NT;
        const float2 a = st[i];
        const float pr = a.x * a.x + a.y * a.y;
        #pragma unroll
        for (int w = 0; w < NQ; ++w)
            zl[w] += ((i >> (11 - w)) & 1) ? -pr : pr;
    }
    #pragma unroll
    for (int w = 0; w < NQ; ++w) {
        float s = zl[w];
        #pragma unroll
        for (int m = 32; m; m >>= 1) s += __shfl_xor(s, m, 64);
        if (lane == 0) red[w * 4 + wid] = s;
    }
    __syncthreads();
    if (tid < NQ)
        qz[tid] = red[tid * 4 + 0] + red[tid * 4 + 1] + red[tid * 4 + 2] + red[tid * 4 + 3];
    __syncthreads();

    // ---- 7. MLP: relu(q @ h1_w.T + h1_b) ----
    {
        float s = h1_b[tid];
        #pragma unroll
        for (int k = 0; k < NQ; ++k) s += qz[k] * h1_w[tid * NQ + k];
        z1[tid] = s > 0.f ? s : 0.f;
    }
    __syncthreads();

    // ---- 8. out = z1 @ h2_w.T + h2_b : 28 outputs, 7 per wave ----
    #pragma unroll
    for (int jj = 0; jj < 7; ++jj) {
        const int j = wid * 7 + jj;
        const float* wr = h2_w + j * 256;
        float s = 0.f;
        #pragma unroll
        for (int k = 0; k < 4; ++k) s += z1[lane + k * 64] * wr[lane + k * 64];
        #pragma unroll
        for (int m = 32; m; m >>= 1) s += __shfl_xor(s, m, 64);
        if (lane == 0) out[(size_t)b * NLAB + j] = s + h2_b[j];
    }
}

extern "C" void kernel_launch(void* const* d_in, const int* in_sizes, int n_in,
                              void* d_out, int out_size, void* d_ws, size_t ws_size,
                              hipStream_t stream) {
    const float* x      = (const float*)d_in[0];
    const float* proj_w = (const float*)d_in[1];
    const float* proj_b = (const float*)d_in[2];
    const float* ln_w   = (const float*)d_in[3];
    const float* ln_b   = (const float*)d_in[4];
    const float* q_w    = (const float*)d_in[5];
    const float* h1_w   = (const float*)d_in[6];
    const float* h1_b   = (const float*)d_in[7];
    const float* h2_w   = (const float*)d_in[8];
    const float* h2_b   = (const float*)d_in[9];
    float* out = (float*)d_out;

    const int B = in_sizes[0] / D_IN;   // 512
    hybrid_fused<<<dim3(B), dim3(NT), 0, stream>>>(
        x, proj_w, proj_b, ln_w, ln_b, q_w,
        h1_w, h1_b, h2_w, h2_b, out);
}

// Round 2
// 49.377 us; speedup vs baseline: 1.7878x; 1.7878x over previous
//
#include <hip/hip_runtime.h>
#include <math.h>

#define D_IN 768
#define NQ 12
#define NST 4096
#define NT 256
#define NLAB 28
#define NPH 16

// ---- phase schedule: which 4 state-bits are register-resident ----
// PB[p][k] = state bit held in register-index bit k (sorted ascending)
static constexpr int PB[NPH][4] = {
    {8,9,10,11}, {5,6,7,8},  {2,3,4,5},  {0,1,2,11},
    {8,9,10,11}, {6,7,8,9},  {4,5,6,7},  {2,3,4,5},
    {0,1,2,3},   {0,1,10,11},{7,8,10,11},{5,6,8,9},
    {3,4,6,7},   {1,2,4,5},  {0,2,3,11}, {0,1,9,10}};
// PT[p][j] = state bit holding thread-id bit j (the 8 non-register bits, asc)
static constexpr int PT[NPH][8] = {
    {0,1,2,3,4,5,6,7},  {0,1,2,3,4,9,10,11},{0,1,6,7,8,9,10,11},{3,4,5,6,7,8,9,10},
    {0,1,2,3,4,5,6,7},  {0,1,2,3,4,5,10,11},{0,1,2,3,8,9,10,11},{0,1,6,7,8,9,10,11},
    {4,5,6,7,8,9,10,11},{2,3,4,5,6,7,8,9},  {0,1,2,3,4,5,6,9},  {0,1,2,3,4,7,10,11},
    {0,1,2,5,8,9,10,11},{0,3,6,7,8,9,10,11},{1,4,5,6,7,8,9,10}, {2,3,4,5,6,7,8,11}};
// gates per phase, in circuit order. {type, a, b}:
//   type 0: RY   a=wire        b=reg-bit
//   type 1: ROT  a=l*12+w      b=reg-bit
//   type 2: CNOT a=ctrl regbit b=tgt regbit
//   type 3: end sentinel
static constexpr int GATES[NPH][11][3] = {
  // P0 bits{8..11}: RY w0..3, Rot l0 w0..3, CNOT(11,10)(10,9)(9,8)
  {{0,0,3},{0,1,2},{0,2,1},{0,3,0},{1,0,3},{1,1,2},{1,2,1},{1,3,0},{2,3,2},{2,2,1},{2,1,0}},
  // P1 bits{5..8}: RY w4..6, Rot w4..6, CNOT(8,7)(7,6)(6,5)
  {{0,4,2},{0,5,1},{0,6,0},{1,4,2},{1,5,1},{1,6,0},{2,3,2},{2,2,1},{2,1,0},{3,0,0},{3,0,0}},
  // P2 bits{2..5}: RY w7..9, Rot w7..9, CNOT(5,4)(4,3)(3,2)
  {{0,7,2},{0,8,1},{0,9,0},{1,7,2},{1,8,1},{1,9,0},{2,3,2},{2,2,1},{2,1,0},{3,0,0},{3,0,0}},
  // P3 bits{0,1,2,11}: RY w10,w11, Rot w10,w11, CNOT(2,1)(1,0)(0,11)
  {{0,10,1},{0,11,0},{1,10,1},{1,11,0},{2,2,1},{2,1,0},{2,0,3},{3,0,0},{3,0,0},{3,0,0},{3,0,0}},
  // P4 bits{8..11}: Rot l1 w0..3, CNOT(11,9)(10,8)
  {{1,12,3},{1,13,2},{1,14,1},{1,15,0},{2,3,1},{2,2,0},{3,0,0},{3,0,0},{3,0,0},{3,0,0},{3,0,0}},
  // P5 bits{6..9}: Rot w4,w5, CNOT(9,7)(8,6)
  {{1,16,1},{1,17,0},{2,3,1},{2,2,0},{3,0,0},{3,0,0},{3,0,0},{3,0,0},{3,0,0},{3,0,0},{3,0,0}},
  // P6 bits{4..7}: Rot w6,w7, CNOT(7,5)(6,4)
  {{1,18,1},{1,19,0},{2,3,1},{2,2,0},{3,0,0},{3,0,0},{3,0,0},{3,0,0},{3,0,0},{3,0,0},{3,0,0}},
  // P7 bits{2..5}: Rot w8,w9, CNOT(5,3)(4,2)
  {{1,20,1},{1,21,0},{2,3,1},{2,2,0},{3,0,0},{3,0,0},{3,0,0},{3,0,0},{3,0,0},{3,0,0},{3,0,0}},
  // P8 bits{0..3}: Rot w10,w11, CNOT(3,1)(2,0)
  {{1,22,1},{1,23,0},{2,3,1},{2,2,0},{3,0,0},{3,0,0},{3,0,0},{3,0,0},{3,0,0},{3,0,0},{3,0,0}},
  // P9 bits{0,1,10,11}: CNOT(1,11)(0,10)
  {{2,1,3},{2,0,2},{3,0,0},{3,0,0},{3,0,0},{3,0,0},{3,0,0},{3,0,0},{3,0,0},{3,0,0},{3,0,0}},
  // P10 bits{7,8,10,11}: Rot l2 w0,w1,w3,w4, CNOT(11,8)(10,7)
  {{1,24,3},{1,25,2},{1,27,1},{1,28,0},{2,3,1},{2,2,0},{3,0,0},{3,0,0},{3,0,0},{3,0,0},{3,0,0}},
  // P11 bits{5,6,8,9}: Rot w2,w5,w6, CNOT(9,6)(8,5)
  {{1,26,3},{1,29,1},{1,30,0},{2,3,1},{2,2,0},{3,0,0},{3,0,0},{3,0,0},{3,0,0},{3,0,0},{3,0,0}},
  // P12 bits{3,4,6,7}: Rot w7,w8, CNOT(7,4)(6,3)
  {{1,31,1},{1,32,0},{2,3,1},{2,2,0},{3,0,0},{3,0,0},{3,0,0},{3,0,0},{3,0,0},{3,0,0},{3,0,0}},
  // P13 bits{1,2,4,5}: Rot w9,w10, CNOT(5,2)(4,1)
  {{1,33,1},{1,34,0},{2,3,1},{2,2,0},{3,0,0},{3,0,0},{3,0,0},{3,0,0},{3,0,0},{3,0,0},{3,0,0}},
  // P14 bits{0,2,3,11}: Rot w11, CNOT(3,0)(2,11)
  {{1,35,0},{2,2,0},{2,1,3},{3,0,0},{3,0,0},{3,0,0},{3,0,0},{3,0,0},{3,0,0},{3,0,0},{3,0,0}},
  // P15 bits{0,1,9,10}: CNOT(1,10)(0,9)
  {{2,1,3},{2,0,2},{3,0,0},{3,0,0},{3,0,0},{3,0,0},{3,0,0},{3,0,0},{3,0,0},{3,0,0},{3,0,0}}};

__device__ __forceinline__ int swz(int i) { return i ^ ((i >> 4) & 15); }

template <int P>
__device__ __forceinline__ void remap_into(float2 (&amp)[16], int tid, float2* st) {
    // write with mapping P-1, read with mapping P  (callers ensure barriers)
    int tso = 0, tsn = 0;
#pragma unroll
    for (int j = 0; j < 8; ++j) {
        tso |= ((tid >> j) & 1) << PT[P - 1][j];
        tsn |= ((tid >> j) & 1) << PT[P][j];
    }
#pragma unroll
    for (int r = 0; r < 16; ++r) {
        int rs = 0;
#pragma unroll
        for (int k = 0; k < 4; ++k) rs |= ((r >> k) & 1) << PB[P - 1][k];
        st[swz(tso | rs)] = amp[r];
    }
    __syncthreads();
#pragma unroll
    for (int r = 0; r < 16; ++r) {
        int rs = 0;
#pragma unroll
        for (int k = 0; k < 4; ++k) rs |= ((r >> k) & 1) << PB[P][k];
        amp[r] = st[swz(tsn | rs)];
    }
    __syncthreads();
}

template <int P>
__device__ __forceinline__ void phase_gates(float2 (&amp)[16], const float* cy,
                                            const float* sy, const float (*rotU)[8]) {
#pragma unroll
    for (int g = 0; g < 11; ++g) {
        const int t = GATES[P][g][0];
        if (t == 0) {  // RY, real 2x2
            const int w = GATES[P][g][1];
            const int m = 1 << GATES[P][g][2];
            const float c = cy[w], s = sy[w];
#pragma unroll
            for (int r = 0; r < 16; ++r)
                if (!(r & m)) {
                    const float2 a0 = amp[r], a1 = amp[r | m];
                    amp[r]     = make_float2(c * a0.x - s * a1.x, c * a0.y - s * a1.y);
                    amp[r | m] = make_float2(s * a0.x + c * a1.x, s * a0.y + c * a1.y);
                }
        } else if (t == 1) {  // Rot, complex 2x2
            const float* U = rotU[GATES[P][g][1]];
            const float u00r = U[0], u00i = U[1], u01r = U[2], u01i = U[3];
            const float u10r = U[4], u10i = U[5], u11r = U[6], u11i = U[7];
            const int m = 1 << GATES[P][g][2];
#pragma unroll
            for (int r = 0; r < 16; ++r)
                if (!(r & m)) {
                    const float2 a0 = amp[r], a1 = amp[r | m];
                    float2 n0, n1;
                    n0.x = u00r * a0.x - u00i * a0.y + u01r * a1.x - u01i * a1.y;
                    n0.y = u00r * a0.y + u00i * a0.x + u01r * a1.y + u01i * a1.x;
                    n1.x = u10r * a0.x - u10i * a0.y + u11r * a1.x - u11i * a1.y;
                    n1.y = u10r * a0.y + u10i * a0.x + u11r * a1.y + u11i * a1.x;
                    amp[r] = n0;
                    amp[r | m] = n1;
                }
        } else if (t == 2) {  // CNOT inside register set: pure register swap
            const int mc = 1 << GATES[P][g][1];
            const int mt = 1 << GATES[P][g][2];
#pragma unroll
            for (int r = 0; r < 16; ++r)
                if ((r & mc) && !(r & mt)) {
                    const float2 tmp = amp[r];
                    amp[r] = amp[r | mt];
                    amp[r | mt] = tmp;
                }
        }
    }
}

template <int P>
__device__ __forceinline__ void run_phases(float2 (&amp)[16], int tid, float2* st,
                                           const float* cy, const float* sy,
                                           const float (*rotU)[8]) {
    if constexpr (P > 0) remap_into<P>(amp, tid, st);
    phase_gates<P>(amp, cy, sy, rotU);
    if constexpr (P + 1 < NPH) run_phases<P + 1>(amp, tid, st, cy, sy, rotU);
}

__global__ __launch_bounds__(NT) void hybrid_fused(
    const float* __restrict__ x, const float* __restrict__ proj_w,
    const float* __restrict__ proj_b, const float* __restrict__ ln_w,
    const float* __restrict__ ln_b, const float* __restrict__ q_w,
    const float* __restrict__ h1_w, const float* __restrict__ h1_b,
    const float* __restrict__ h2_w, const float* __restrict__ h2_b,
    float* __restrict__ out) {
    __shared__ float2 st[NST];         // 32 KB remap buffer
    __shared__ float rotU[3 * NQ][8];  // Rot gate matrices
    __shared__ float hbuf[NQ];
    __shared__ float cy[NQ], sy[NQ];
    __shared__ float red[4 * NQ];
    __shared__ float z1[256];
    __shared__ float qz[NQ];

    const int b = blockIdx.x;
    const int tid = threadIdx.x;
    const int lane = tid & 63;
    const int wid = tid >> 6;

    // ---- 1. projection h[j] = tanh(x[b] . proj_w[j] + proj_b[j]) ----
    {
        const float* xr = x + (size_t)b * D_IN;
#pragma unroll
        for (int jj = 0; jj < 3; ++jj) {
            const int j = wid * 3 + jj;
            const float* wr = proj_w + j * D_IN;
            float s = 0.f;
#pragma unroll
            for (int k = 0; k < D_IN / 64; ++k)
                s += xr[lane + k * 64] * wr[lane + k * 64];
#pragma unroll
            for (int m = 32; m; m >>= 1) s += __shfl_xor(s, m, 64);
            if (lane == 0) hbuf[j] = tanhf(s + proj_b[j]);
        }
    }
    __syncthreads();

    // ---- 2. LayerNorm -> RY coeffs; Rot matrices ----
    if (tid < NQ) {
        float mu = 0.f;
#pragma unroll
        for (int k = 0; k < NQ; ++k) mu += hbuf[k];
        mu *= (1.f / NQ);
        float var = 0.f;
#pragma unroll
        for (int k = 0; k < NQ; ++k) {
            const float d = hbuf[k] - mu;
            var += d * d;
        }
        var *= (1.f / NQ);
        const float inv = 1.0f / sqrtf(var + 1e-5f);
        const float ang = (hbuf[tid] - mu) * inv * ln_w[tid] + ln_b[tid];
        cy[tid] = cosf(0.5f * ang);
        sy[tid] = sinf(0.5f * ang);
    }
    if (tid < 3 * NQ) {
        const float phi = q_w[tid * 3 + 0];
        const float th  = q_w[tid * 3 + 1];
        const float om  = q_w[tid * 3 + 2];
        const float c = cosf(0.5f * th), s = sinf(0.5f * th);
        const float a = 0.5f * (phi + om);
        const float bb = 0.5f * (phi - om);
        const float ca = cosf(a), sa = sinf(a);
        const float cb = cosf(bb), sb = sinf(bb);
        float* U = rotU[tid];
        U[0] = c * ca;  U[1] = -c * sa;   // U00 = ep*c
        U[2] = -s * cb; U[3] = -s * sb;   // U01 = -conj(em)*s
        U[4] = s * cb;  U[5] = -s * sb;   // U10 = em*s
        U[6] = c * ca;  U[7] = c * sa;    // U11 = conj(ep)*c
    }
    __syncthreads();

    // ---- 3. state in registers: 16 amps/thread; |0...0> ----
    float2 amp[16];
#pragma unroll
    for (int r = 0; r < 16; ++r) amp[r] = make_float2(0.f, 0.f);
    if (tid == 0) amp[0] = make_float2(1.f, 0.f);

    // ---- 4. all 84 gates in 16 phases (15 LDS remaps) ----
    run_phases<0>(amp, tid, st, cy, sy, rotU);

    // ---- 5. PauliZ expectations (mapping of final phase NPH-1) ----
    {
        int ts = 0;
#pragma unroll
        for (int j = 0; j < 8; ++j) ts |= ((tid >> j) & 1) << PT[NPH - 1][j];
        float zl[NQ];
#pragma unroll
        for (int w = 0; w < NQ; ++w) zl[w] = 0.f;
#pragma unroll
        for (int r = 0; r < 16; ++r) {
            int rs = 0;
#pragma unroll
            for (int k = 0; k < 4; ++k) rs |= ((r >> k) & 1) << PB[NPH - 1][k];
            const int i = ts | rs;
            const float2 a = amp[r];
            const float pr = a.x * a.x + a.y * a.y;
#pragma unroll
            for (int w = 0; w < NQ; ++w) zl[w] += ((i >> (11 - w)) & 1) ? -pr : pr;
        }
#pragma unroll
        for (int w = 0; w < NQ; ++w) {
            float s = zl[w];
#pragma unroll
            for (int m = 32; m; m >>= 1) s += __shfl_xor(s, m, 64);
            if (lane == 0) red[w * 4 + wid] = s;
        }
    }
    __syncthreads();
    if (tid < NQ)
        qz[tid] = red[tid * 4 + 0] + red[tid * 4 + 1] + red[tid * 4 + 2] + red[tid * 4 + 3];
    __syncthreads();

    // ---- 6. MLP hidden: relu(q @ h1_w.T + h1_b) ----
    {
        float s = h1_b[tid];
#pragma unroll
        for (int k = 0; k < NQ; ++k) s += qz[k] * h1_w[tid * NQ + k];
        z1[tid] = s > 0.f ? s : 0.f;
    }
    __syncthreads();

    // ---- 7. out = z1 @ h2_w.T + h2_b ----
#pragma unroll
    for (int jj = 0; jj < 7; ++jj) {
        const int j = wid * 7 + jj;
        const float* wr = h2_w + j * 256;
        float s = 0.f;
#pragma unroll
        for (int k = 0; k < 4; ++k) s += z1[lane + k * 64] * wr[lane + k * 64];
#pragma unroll
        for (int m = 32; m; m >>= 1) s += __shfl_xor(s, m, 64);
        if (lane == 0) out[(size_t)b * NLAB + j] = s + h2_b[j];
    }
}

extern "C" void kernel_launch(void* const* d_in, const int* in_sizes, int n_in,
                              void* d_out, int out_size, void* d_ws, size_t ws_size,
                              hipStream_t stream) {
    const float* x      = (const float*)d_in[0];
    const float* proj_w = (const float*)d_in[1];
    const float* proj_b = (const float*)d_in[2];
    const float* ln_w   = (const float*)d_in[3];
    const float* ln_b   = (const float*)d_in[4];
    const float* q_w    = (const float*)d_in[5];
    const float* h1_w   = (const float*)d_in[6];
    const float* h1_b   = (const float*)d_in[7];
    const float* h2_w   = (const float*)d_in[8];
    const float* h2_b   = (const float*)d_in[9];
    float* out = (float*)d_out;

    const int B = in_sizes[0] / D_IN;  // 512
    hybrid_fused<<<dim3(B), dim3(NT), 0, stream>>>(x, proj_w, proj_b, ln_w, ln_b,
                                                   q_w, h1_w, h1_b, h2_w, h2_b, out);
}